// Round 2
// baseline (649.239 us; speedup 1.0000x reference)
//
#include <hip/hip_runtime.h>

#define DEVI static __device__ __forceinline__

namespace {

constexpr int NV   = 120000;
constexpr int ND   = 30000;
constexpr int NV2  = 60000;
constexpr int NPTS = 400000;
constexpr int C    = 128;

DEVI float lrelu(float x){ return x > 0.f ? x : 0.1f*x; }

// ---- scatter x = features+v_fea into downsample buckets (segment sum + count)
__global__ void k_scatter_ds(const float* __restrict__ f, const float* __restrict__ vf,
                             const int* __restrict__ inv, float* __restrict__ ds_sum,
                             float* __restrict__ ds_cnt){
  int v = blockIdx.x * 2 + (threadIdx.x >> 7);
  int c = threadIdx.x & 127;
  int d = inv[v];
  size_t idx = (size_t)v * C + c;
  float x = f[idx] + vf[idx];
  atomicAdd(ds_sum + (size_t)d * C + c, x);
  if (c == 0) atomicAdd(ds_cnt + d, 1.f);
}

// ---- generic row-tiled f32 GEMM: out[M,N] = epilogue( pre(A)[M,K] @ W[K,N] )
// BM=64 rows per block, 256 threads. A tile staged transposed in LDS.
template<int K, int N, bool LRELU, bool STATS, bool PRESCALE, bool DIVCNT,
         bool TWOIN, bool ROWADD, bool BIAS>
__global__ __launch_bounds__(256) void k_gemm(
    const float* __restrict__ A, const float* __restrict__ A2,
    const float* __restrict__ cnt, const float* __restrict__ scale,
    const float* __restrict__ shift, const float* __restrict__ W,
    const float* __restrict__ bias, const float* __restrict__ rowtab,
    const int* __restrict__ rowidx, float* __restrict__ out,
    float* __restrict__ stats, int M)
{
  constexpr int BM = 64;
  constexpr int G  = N / 4;      // column quads per row of threads
  constexpr int TY = 256 / G;    // row groups
  constexpr int R  = BM / TY;    // rows per thread (4 or 8)
  constexpr int KV = K / 4;

  __shared__ float At[K][BM + 4];            // transposed A tile
  __shared__ int   sidx[ROWADD ? BM : 1];
  __shared__ float red[STATS ? 2 * TY * N : 1];

  const int tid  = threadIdx.x;
  const int tx   = tid % G;
  const int ty   = tid / G;
  const int row0 = blockIdx.x * BM;

  // ---- stage A tile (apply divide-by-count / prescale / two-input add here)
  for (int i = tid; i < BM * KV; i += 256){
    int r  = i / KV;
    int kc = (i % KV) * 4;
    int row = row0 + r;
    float4 v = make_float4(0.f, 0.f, 0.f, 0.f);
    if (row < M){
      v = *(const float4*)(A + (size_t)row * K + kc);
      if constexpr (TWOIN){
        float4 w = *(const float4*)(A2 + (size_t)row * K + kc);
        v.x += w.x; v.y += w.y; v.z += w.z; v.w += w.w;
      }
      if constexpr (DIVCNT){
        float cc = fmaxf(cnt[row], 1.f);
        float ic = 1.f / cc;
        v.x *= ic; v.y *= ic; v.z *= ic; v.w *= ic;
      }
      if constexpr (PRESCALE){
        v.x = v.x * scale[kc + 0] + shift[kc + 0];
        v.y = v.y * scale[kc + 1] + shift[kc + 1];
        v.z = v.z * scale[kc + 2] + shift[kc + 2];
        v.w = v.w * scale[kc + 3] + shift[kc + 3];
      }
    }
    At[kc + 0][r] = v.x; At[kc + 1][r] = v.y;
    At[kc + 2][r] = v.z; At[kc + 3][r] = v.w;
  }
  if constexpr (ROWADD){
    for (int i = tid; i < BM; i += 256){
      int row = row0 + i;
      sidx[i] = row < M ? rowidx[row] : 0;
    }
  }
  __syncthreads();

  float acc[R][4];
  #pragma unroll
  for (int r = 0; r < R; ++r)
    for (int j = 0; j < 4; ++j) acc[r][j] = 0.f;

  #pragma unroll 4
  for (int k = 0; k < K; ++k){
    float4 w4 = *(const float4*)(W + (size_t)k * N + tx * 4);
    const float4* ap = (const float4*)&At[k][ty * R];
    #pragma unroll
    for (int rq = 0; rq < R / 4; ++rq){
      float4 a4 = ap[rq];
      float av[4] = {a4.x, a4.y, a4.z, a4.w};
      #pragma unroll
      for (int rr = 0; rr < 4; ++rr){
        int r = rq * 4 + rr;
        acc[r][0] += av[rr] * w4.x;
        acc[r][1] += av[rr] * w4.y;
        acc[r][2] += av[rr] * w4.z;
        acc[r][3] += av[rr] * w4.w;
      }
    }
  }

  float bx[4] = {0.f, 0.f, 0.f, 0.f};
  if constexpr (BIAS){
    float4 b = *(const float4*)(bias + tx * 4);
    bx[0] = b.x; bx[1] = b.y; bx[2] = b.z; bx[3] = b.w;
  }

  float ps[4] = {0.f,0.f,0.f,0.f}, pq[4] = {0.f,0.f,0.f,0.f};
  #pragma unroll
  for (int r = 0; r < R; ++r){
    int row = row0 + ty * R + r;
    if (row < M){
      float o[4];
      #pragma unroll
      for (int j = 0; j < 4; ++j) o[j] = acc[r][j] + bx[j];
      if constexpr (ROWADD){
        int d = sidx[ty * R + r];
        float4 tv = *(const float4*)(rowtab + (size_t)d * N + tx * 4);
        o[0] += tv.x; o[1] += tv.y; o[2] += tv.z; o[3] += tv.w;
      }
      if constexpr (LRELU){
        #pragma unroll
        for (int j = 0; j < 4; ++j) o[j] = lrelu(o[j]);
      }
      *(float4*)(out + (size_t)row * N + tx * 4) = make_float4(o[0], o[1], o[2], o[3]);
      if constexpr (STATS){
        #pragma unroll
        for (int j = 0; j < 4; ++j){ ps[j] += o[j]; pq[j] += o[j] * o[j]; }
      }
    }
  }

  if constexpr (STATS){
    #pragma unroll
    for (int j = 0; j < 4; ++j){
      red[(0 * TY + ty) * N + tx * 4 + j] = ps[j];
      red[(1 * TY + ty) * N + tx * 4 + j] = pq[j];
    }
    __syncthreads();
    for (int col = tid; col < N; col += 256){
      float s = 0.f, q = 0.f;
      #pragma unroll
      for (int t2 = 0; t2 < TY; ++t2){
        s += red[(0 * TY + t2) * N + col];
        q += red[(1 * TY + t2) * N + col];
      }
      atomicAdd(&stats[col], s);
      atomicAdd(&stats[N + col], q);
    }
  }
}

// ---- BN param folding: scale = g*rsqrt(var+eps), shift = beta - mean*scale
__global__ void k_bn(const float* __restrict__ stats, const float* __restrict__ g,
                     const float* __restrict__ beta, float* __restrict__ scale,
                     float* __restrict__ shift, float inv_n){
  int c = threadIdx.x;   // 64 threads
  float mean = stats[c] * inv_n;
  float var  = stats[64 + c] * inv_n - mean * mean;
  float sc   = g[c] * rsqrtf(var + 1e-5f);
  scale[c] = sc;
  shift[c] = beta[c] - mean * sc;
}

// ---- scatter z[cil[p]] into next-scale segments (sum + count)
__global__ void k_scatter_p(const float* __restrict__ z, const int* __restrict__ cil,
                            const int* __restrict__ cin, float* __restrict__ p_sum,
                             float* __restrict__ p_cnt){
  int p = blockIdx.x * 2 + (threadIdx.x >> 7);
  int c = threadIdx.x & 127;
  int v = cil[p];
  int s = cin[p];
  atomicAdd(p_sum + (size_t)s * C + c, z[(size_t)v * C + c]);
  if (c == 0) atomicAdd(p_cnt + s, 1.f);
}

// ---- out[p] = (float) p_mean[cin[p]]   (divide fused here is wrong — p read many
//      times per segment; keep separate divide pass for O(NV2) divides)
__global__ void k_divcnt(float* __restrict__ p, const float* __restrict__ cnt){
  int i = blockIdx.x * blockDim.x + threadIdx.x;
  if (i < NV2 * (C / 4)){
    int s = i / (C / 4);
    float cc = fmaxf(cnt[s], 1.f);
    float ic = 1.f / cc;
    float4 v = *(float4*)(p + (size_t)i * 4);
    v.x *= ic; v.y *= ic; v.z *= ic; v.w *= ic;
    *(float4*)(p + (size_t)i * 4) = v;
  }
}

// ---- out[p] = p_mean[cin[p]]  (f32 output!)
__global__ void k_gather_out(const float* __restrict__ pm, const int* __restrict__ cin,
                             float* __restrict__ out){
  int i = blockIdx.x * blockDim.x + threadIdx.x;   // over NPTS*(C/4)
  if (i < NPTS * (C / 4)){
    int p = i / (C / 4);
    int q = i % (C / 4);
    int s = cin[p];
    float4 v = *(const float4*)(pm + (size_t)s * C + q * 4);
    *(float4*)(out + (size_t)i * 4) = v;
  }
}

inline int cdiv(int a, int b){ return (a + b - 1) / b; }

} // namespace

extern "C" void kernel_launch(void* const* d_in, const int* in_sizes, int n_in,
                              void* d_out, int out_size, void* d_ws, size_t ws_size,
                              hipStream_t stream){
  const float* features = (const float*)d_in[0];
  const float* v_fea    = (const float*)d_in[1];
  const int*   inv      = (const int*)d_in[2];
  const int*   cil      = (const int*)d_in[3];
  const int*   cin      = (const int*)d_in[4];
  const float* W_in  = (const float*)d_in[5];
  const float* b_in  = (const float*)d_in[6];
  const float* W1    = (const float*)d_in[7];
  const float* b1    = (const float*)d_in[8];
  const float* g1    = (const float*)d_in[9];
  const float* beta1 = (const float*)d_in[10];
  const float* W2    = (const float*)d_in[11];
  const float* b2    = (const float*)d_in[12];
  const float* g2    = (const float*)d_in[13];
  const float* beta2 = (const float*)d_in[14];
  const float* W3    = (const float*)d_in[15];
  const float* b3    = (const float*)d_in[16];
  const float* Wo1   = (const float*)d_in[17];
  const float* bo1   = (const float*)d_in[18];
  const float* Wo2   = (const float*)d_in[19];
  const float* bo2   = (const float*)d_in[20];

  float* ws = (float*)d_ws;
  // workspace layout (floats), with aliasing to cut footprint to ~108 MB:
  //   ds_sum [ND*C]  — later reused as t [ND*C] (step 5+)
  //   ds_cnt [ND]
  //   p_cnt  [NV2]
  //   stats  [512]
  //   p_sum  [NV2*C] — earlier reused as h1 [ND*64], h2 [ND*64] (steps 2-4)
  //   big    [NV*C]  — hm -> identity -> y -> z
  float* ds_sum = ws;                               // ND*C = 3,840,000
  float* ds_cnt = ds_sum + (size_t)ND * C;          // 30,000
  float* p_cnt  = ds_cnt + ND;                      // 60,000
  float* stats  = p_cnt + NV2;                      // 512
  float* p_sum  = stats + 512;                      // NV2*C = 7,680,000
  float* big    = p_sum + (size_t)NV2 * C;          // NV*C = 15,360,000

  float* t      = ds_sum;                           // alias (after step 2)
  float* h1     = p_sum;                            // alias (before step 9)
  float* h2     = h1 + (size_t)ND * 64;             // alias
  float* stats1 = stats;          // sum1[64], sq1[64]
  float* stats2 = stats + 128;    // sum2[64], sq2[64]
  float* scale1 = stats + 256;
  float* shift1 = stats + 320;
  float* scale2 = stats + 384;
  float* shift2 = stats + 448;

  // zero ds accumulators + p_cnt + BN stat sums (contiguous prefix)
  size_t zero1 = ((size_t)ND * C + ND + NV2 + 512) * sizeof(float);
  hipMemsetAsync(ds_sum, 0, zero1, stream);

  // 1) downsample segment sums
  k_scatter_ds<<<NV / 2, 256, 0, stream>>>(features, v_fea, inv, ds_sum, ds_cnt);

  // 2) h1 = lrelu(ds @ W1 + b1), BN1 stats
  k_gemm<128, 64, true, true, false, true, false, false, true>
      <<<cdiv(ND, 64), 256, 0, stream>>>(ds_sum, nullptr, ds_cnt, nullptr, nullptr,
                                          W1, b1, nullptr, nullptr, h1, stats1, ND);
  k_bn<<<1, 64, 0, stream>>>(stats1, g1, beta1, scale1, shift1, 1.f / ND);

  // 3) h2 = lrelu(bn1(h1) @ W2 + b2), BN2 stats
  k_gemm<64, 64, true, true, true, false, false, false, true>
      <<<cdiv(ND, 64), 256, 0, stream>>>(h1, nullptr, nullptr, scale1, shift1,
                                          W2, b2, nullptr, nullptr, h2, stats2, ND);
  k_bn<<<1, 64, 0, stream>>>(stats2, g2, beta2, scale2, shift2, 1.f / ND);

  // 4) hm = lrelu(bn2(h2) @ W3 + b3)  -> big
  k_gemm<64, 128, true, false, true, false, false, false, true>
      <<<cdiv(ND, 64), 256, 0, stream>>>(h2, nullptr, nullptr, scale2, shift2,
                                          W3, b3, nullptr, nullptr, big, nullptr, ND);

  // 5) t = hm @ Wo1_bot + bo1   (t aliases ds_sum, which is dead now)
  k_gemm<128, 128, false, false, false, false, false, false, true>
      <<<cdiv(ND, 64), 256, 0, stream>>>(big, nullptr, nullptr, nullptr, nullptr,
                                          Wo1 + (size_t)C * C, bo1, nullptr, nullptr,
                                          t, nullptr, ND);

  // p_sum aliases h1/h2 — zero it now that steps 2-4 consumed them
  hipMemsetAsync(p_sum, 0, (size_t)NV2 * C * sizeof(float), stream);

  // 6) identity = lrelu((features+v_fea) @ W_in + b_in) -> big
  k_gemm<128, 128, true, false, false, false, true, false, true>
      <<<cdiv(NV, 64), 256, 0, stream>>>(features, v_fea, nullptr, nullptr, nullptr,
                                          W_in, b_in, nullptr, nullptr, big, nullptr, NV);

  // 7) y = lrelu(identity @ Wo1_top + t[inv])  (bo1 already in t) -> big in place
  k_gemm<128, 128, true, false, false, false, false, true, false>
      <<<cdiv(NV, 64), 256, 0, stream>>>(big, nullptr, nullptr, nullptr, nullptr,
                                          Wo1, nullptr, t, inv, big, nullptr, NV);

  // 8) z = y @ Wo2 + bo2 -> big in place
  k_gemm<128, 128, false, false, false, false, false, false, true>
      <<<cdiv(NV, 64), 256, 0, stream>>>(big, nullptr, nullptr, nullptr, nullptr,
                                          Wo2, bo2, nullptr, nullptr, big, nullptr, NV);

  // 9) scatter z[cil] into next-scale segments
  k_scatter_p<<<NPTS / 2, 256, 0, stream>>>(big, cil, cin, p_sum, p_cnt);

  // 10) mean
  k_divcnt<<<cdiv(NV2 * (C / 4), 256), 256, 0, stream>>>(p_sum, p_cnt);

  // 11) gather to points (f32 output)
  k_gather_out<<<cdiv(NPTS * (C / 4), 256), 256, 0, stream>>>(p_sum, cin,
                                                              (float*)d_out);

  (void)in_sizes; (void)n_in; (void)out_size; (void)ws_size;
}